// Round 7
// baseline (327.193 us; speedup 1.0000x reference)
//
#include <hip/hip_runtime.h>
#include <hip/hip_bf16.h>
#include <math.h>

// Problem constants (from reference)
#define BATCH   64
#define NNODES  256
#define HID     256
#define HEADS   4
#define CDIM    64
#define NEDGES  8192
#define NEG_SLOPE 0.2f
#define EPS_BN 1e-5f

// All intermediate activations use NODE-MAJOR layout: row = node*64 + batch.

typedef __bf16 bf16_t;
typedef __bf16 bf16x8 __attribute__((ext_vector_type(8)));
typedef float  f32x4  __attribute__((ext_vector_type(4)));

__device__ __forceinline__ float gelu_f(float x) {
    return 0.5f * x * (1.0f + erff(x * 0.70710678118654752440f));
}

// LDS bank swizzle for 16B chunks: rows r,r+8 never alias; frag reads are
// 2-way max (free). Row stride = 4 chunks = 64 B, no padding.
#define SWZ(r, c) ((c) ^ ((r) & 3) ^ (((r) >> 2) & 3))

// ---------------------------------------------------------------------------
// Fused CSR build + weight transpose/bf16-convert. Grid 449 x 256 threads.
// ---------------------------------------------------------------------------
__global__ __launch_bounds__(256) void prep_kernel(
        const int* __restrict__ ei,
        const float* __restrict__ W1, const float* __restrict__ Wa,
        const float* __restrict__ Wb, const float* __restrict__ Wc,
        const float* __restrict__ Wd,
        int* __restrict__ noff, int* __restrict__ csrc,
        bf16_t* __restrict__ T1, bf16_t* __restrict__ Ta,
        bf16_t* __restrict__ Tb, bf16_t* __restrict__ Tc,
        bf16_t* __restrict__ Td) {
    const int bx = blockIdx.x;
    const int tid = threadIdx.x;
    if (bx == 448) {
        __shared__ int cnt[NNODES];
        __shared__ int off_s[NNODES + 1];
        cnt[tid] = 0;
        __syncthreads();
        for (int e = tid; e < NEDGES; e += 256) atomicAdd(&cnt[ei[NEDGES + e]], 1);
        __syncthreads();
        if (tid == 0) {
            int s = 0;
            for (int i = 0; i < NNODES; ++i) { off_s[i] = s; s += cnt[i]; }
            off_s[NNODES] = s;
        }
        __syncthreads();
        cnt[tid] = off_s[tid];
        noff[tid] = off_s[tid];
        if (tid == 0) noff[NNODES] = off_s[NNODES];
        __syncthreads();
        for (int e = tid; e < NEDGES; e += 256) {
            int d = ei[NEDGES + e];
            int p = atomicAdd(&cnt[d], 1);
            csrc[p] = ei[e];
        }
        return;
    }
    __shared__ float tile[32][33];
    const float* in; bf16_t* out; int K, t;
    if (bx < 192) { in = W1; out = T1; K = 768; t = bx; }
    else {
        int r = bx - 192, mid = r >> 6; t = r & 63; K = 256;
        if (mid == 0) { in = Wa; out = Ta; }
        else if (mid == 1) { in = Wb; out = Tb; }
        else if (mid == 2) { in = Wc; out = Tc; }
        else { in = Wd; out = Td; }
    }
    const int kt = t >> 3, nt = t & 7;
    const int k0 = kt * 32, n0 = nt * 32;
    const int x = tid & 31, y = tid >> 5;
    #pragma unroll
    for (int j = 0; j < 4; ++j)
        tile[y + j * 8][x] = in[(size_t)(k0 + y + j * 8) * 256 + n0 + x];
    __syncthreads();
    #pragma unroll
    for (int j = 0; j < 4; ++j)
        out[(size_t)(n0 + y + j * 8) * K + k0 + x] = (bf16_t)tile[x][y + j * 8];
}

// ---------------------------------------------------------------------------
// MFMA bf16 GEMM, full-width tiles: C[M x 256] = A[M x K] @ B[K x 256].
// Tile 128(M) x 256(N), BK=32; A is fetched from HBM exactly once.
// 4 waves (2x2): wave = 64 rows x 128 cols = 4 m-frags x 8 n-frags
// (32 MFMA : 12 ds_read_b128 per K-iter). XOR-swizzled LDS (no padding).
// PERM: A row = (r%64)*256+r/64 (batch-major input -> node-major output).
// DUAL: blockIdx.x = 0 -> (Bt0,C0,bias0), 1 -> (Bt1,C1,bias1).
// ---------------------------------------------------------------------------
template<int A_F32, int DUAL, int EPI_BN, int PERM>
__global__ __launch_bounds__(256, 2) void gemm_kernel(
        const void* __restrict__ Ap,
        const bf16_t* __restrict__ Bt0, const bf16_t* __restrict__ Bt1,
        bf16_t* __restrict__ C0p, bf16_t* __restrict__ C1p, int K,
        const float* __restrict__ bias0, const float* __restrict__ bias1,
        const float* __restrict__ g, const float* __restrict__ be,
        const float* __restrict__ mu, const float* __restrict__ var) {
    __shared__ bf16_t As[128 * 32];   // [row][4 chunks of 8] swizzled
    __shared__ bf16_t Bs[256 * 32];   // [n][4 chunks of 8]   swizzled
    const int tid  = threadIdx.x;
    const int lane = tid & 63;
    const int wv   = tid >> 6;
    const int wm   = wv >> 1, wn = wv & 1;
    const int mblk = blockIdx.y * 128;
    const bool second = DUAL && (blockIdx.x == 1);
    const bf16_t* Bt = second ? Bt1 : Bt0;
    bf16_t* Cp = second ? C1p : C0p;
    const float* bias = second ? bias1 : bias0;

    f32x4 acc[4][8];
    #pragma unroll
    for (int f = 0; f < 4; ++f)
        #pragma unroll
        for (int t = 0; t < 8; ++t) acc[f][t] = (f32x4){0.f, 0.f, 0.f, 0.f};

    const int arow = tid >> 1;             // 0..127
    const int acb  = (tid & 1) * 2;        // chunk base 0 / 2 (16 elems)
    const int gr   = mblk + arow;
    const int arr  = PERM ? ((gr & 63) * 256 + (gr >> 6)) : gr;
    const int fm   = lane & 15, q = lane >> 4;

    for (int k0 = 0; k0 < K; k0 += 32) {
        bf16x8 v0, v1;
        if (A_F32) {
            const float* ap = (const float*)Ap + (size_t)arr * K + k0 + acb * 8;
            f32x4 a0 = *(const f32x4*)ap;
            f32x4 a1 = *(const f32x4*)(ap + 4);
            f32x4 a2 = *(const f32x4*)(ap + 8);
            f32x4 a3 = *(const f32x4*)(ap + 12);
            #pragma unroll
            for (int j = 0; j < 4; ++j) {
                v0[j] = (bf16_t)a0[j]; v0[4 + j] = (bf16_t)a1[j];
                v1[j] = (bf16_t)a2[j]; v1[4 + j] = (bf16_t)a3[j];
            }
        } else {
            const bf16_t* ap = (const bf16_t*)Ap + (size_t)arr * K + k0 + acb * 8;
            v0 = *(const bf16x8*)ap;
            v1 = *(const bf16x8*)(ap + 8);
        }
        *(bf16x8*)(&As[(arow * 4 + SWZ(arow, acb)) * 8])     = v0;
        *(bf16x8*)(&As[(arow * 4 + SWZ(arow, acb + 1)) * 8]) = v1;

        {
            const bf16_t* bp = Bt + (size_t)tid * K + k0;
            bf16x8 b0 = *(const bf16x8*)bp;
            bf16x8 b1 = *(const bf16x8*)(bp + 8);
            bf16x8 b2 = *(const bf16x8*)(bp + 16);
            bf16x8 b3 = *(const bf16x8*)(bp + 24);
            *(bf16x8*)(&Bs[(tid * 4 + SWZ(tid, 0)) * 8]) = b0;
            *(bf16x8*)(&Bs[(tid * 4 + SWZ(tid, 1)) * 8]) = b1;
            *(bf16x8*)(&Bs[(tid * 4 + SWZ(tid, 2)) * 8]) = b2;
            *(bf16x8*)(&Bs[(tid * 4 + SWZ(tid, 3)) * 8]) = b3;
        }
        __syncthreads();

        bf16x8 af[4], bfv[8];
        #pragma unroll
        for (int f = 0; f < 4; ++f) {
            const int r = wm * 64 + f * 16 + fm;
            af[f] = *(const bf16x8*)(&As[(r * 4 + SWZ(r, q)) * 8]);
        }
        #pragma unroll
        for (int t = 0; t < 8; ++t) {
            const int n = wn * 128 + t * 16 + fm;
            bfv[t] = *(const bf16x8*)(&Bs[(n * 4 + SWZ(n, q)) * 8]);
        }
        #pragma unroll
        for (int f = 0; f < 4; ++f)
            #pragma unroll
            for (int t = 0; t < 8; ++t)
                acc[f][t] = __builtin_amdgcn_mfma_f32_16x16x32_bf16(
                    af[f], bfv[t], acc[f][t], 0, 0, 0);
        __syncthreads();
    }

    const int quad = lane >> 4, cn = lane & 15;
    #pragma unroll
    for (int t = 0; t < 8; ++t) {
        const int n = wn * 128 + t * 16 + cn;
        const float bv = bias[n];
        float scale = 1.0f, shift = 0.0f;
        if (EPI_BN) {
            float s = g[n] * rsqrtf(var[n] + EPS_BN);
            scale = s;
            shift = be[n] - mu[n] * s;
        }
        #pragma unroll
        for (int f = 0; f < 4; ++f) {
            #pragma unroll
            for (int r = 0; r < 4; ++r) {
                const int m = mblk + wm * 64 + f * 16 + quad * 4 + r;
                float val = acc[f][t][r] + bv;
                if (EPI_BN) val = gelu_f(val * scale + shift);
                Cp[(size_t)m * 256 + n] = (bf16_t)val;
            }
        }
    }
}

// ---------------------------------------------------------------------------
// GATv2 edge softmax + aggregate, node-major, XCD-swizzled, 2-chain ILP.
// ---------------------------------------------------------------------------
__global__ __launch_bounds__(256) void edge_kernel(
        const bf16_t* __restrict__ XL, const bf16_t* __restrict__ XR,
        const float* __restrict__ att, const float* __restrict__ bo,
        const int* __restrict__ noff, const int* __restrict__ csrc,
        bf16_t* __restrict__ Hout) {
    const int bid  = blockIdx.x;
    const int i    = bid >> 3;
    const int tid  = threadIdx.x;
    const int w    = tid >> 6;
    const int lane = tid & 63;
    const int bg   = lane >> 3;
    const int cg   = lane & 7;
    const int b    = (bid & 7) * 8 + bg;
    const int cbase = w * CDIM + cg * 8;
    const size_t orow = ((size_t)i * BATCH + b) * HID + cbase;
    const float* bor = bo + cbase;

    const int s0 = noff[i], s1 = noff[i + 1];
    if (s0 == s1) {
        bf16x8 ov;
        #pragma unroll
        for (int q = 0; q < 8; ++q) ov[q] = (bf16_t)gelu_f(bor[q]);
        *(bf16x8*)(Hout + orow) = ov;
        return;
    }

    float a6[8], a4[8], xi[8];
    {
        const float* ar = att + cbase;
        const bf16x8 xr = *(const bf16x8*)(XR + orow);
        #pragma unroll
        for (int q = 0; q < 8; ++q) {
            float a = ar[q];
            a6[q] = 0.6f * a; a4[q] = 0.4f * a;
            xi[q] = (float)xr[q];
        }
    }

    const bf16_t* XLb = XL + (size_t)b * HID + cbase;
    const size_t RSTR = (size_t)BATCH * HID;

    float mA = -1e30f, dA = 0.f, mB = -1e30f, dB = 0.f;
    float accA[8], accB[8];
    #pragma unroll
    for (int q = 0; q < 8; ++q) { accA[q] = 0.f; accB[q] = 0.f; }

    int jA = csrc[s0];
    int jB = csrc[(s0 + 1 < s1) ? s0 + 1 : s0];
    bf16x8 xA = *(const bf16x8*)(XLb + (size_t)jA * RSTR);
    bf16x8 xB = *(const bf16x8*)(XLb + (size_t)jB * RSTR);

    for (int e = s0; e < s1; e += 2) {
        const int nA = (e + 2 < s1) ? e + 2 : s0;
        const int nB = (e + 3 < s1) ? e + 3 : s0;
        const int jnA = csrc[nA], jnB = csrc[nB];
        const bf16x8 xnA = *(const bf16x8*)(XLb + (size_t)jnA * RSTR);
        const bf16x8 xnB = *(const bf16x8*)(XLb + (size_t)jnB * RSTR);

        float fA[8], fB[8];
        #pragma unroll
        for (int q = 0; q < 8; ++q) { fA[q] = (float)xA[q]; fB[q] = (float)xB[q]; }
        float pA = 0.f, pB = 0.f;
        #pragma unroll
        for (int q = 0; q < 8; ++q) {
            const float zA = xi[q] + fA[q];
            const float zB = xi[q] + fB[q];
            pA = fmaf(a6[q], zA, pA);
            pB = fmaf(a6[q], zB, pB);
            pA = fmaf(a4[q], __builtin_fabsf(zA), pA);
            pB = fmaf(a4[q], __builtin_fabsf(zB), pB);
        }
        pA += __shfl_xor(pA, 1, 64);  pB += __shfl_xor(pB, 1, 64);
        pA += __shfl_xor(pA, 2, 64);  pB += __shfl_xor(pB, 2, 64);
        pA += __shfl_xor(pA, 4, 64);  pB += __shfl_xor(pB, 4, 64);

        const float mnA = fmaxf(mA, pA);
        const float alA = __expf(mA - mnA);
        const float wA  = __expf(pA - mnA);
        const float vB  = (e + 1 < s1) ? 1.f : 0.f;
        const float mnB = fmaxf(mB, pB);
        const float alB = __expf(mB - mnB);
        const float wB  = __expf(pB - mnB) * vB;
        dA = dA * alA + wA;
        dB = dB * alB + wB;
        #pragma unroll
        for (int q = 0; q < 8; ++q) {
            accA[q] = fmaf(accA[q], alA, wA * fA[q]);
            accB[q] = fmaf(accB[q], alB, wB * fB[q]);
        }
        mA = mnA; mB = mnB;
        xA = xnA; xB = xnB;
    }

    const float mm = fmaxf(mA, mB);
    const float g1 = __expf(mA - mm);
    const float g2 = __expf(mB - mm);
    const float inv = 1.0f / (dA * g1 + dB * g2 + 1e-16f);
    bf16x8 ov;
    #pragma unroll
    for (int q = 0; q < 8; ++q) {
        const float o = (accA[q] * g1 + accB[q] * g2) * inv + bor[q];
        ov[q] = (bf16_t)gelu_f(o);
    }
    *(bf16x8*)(Hout + orow) = ov;
}

// ---------------------------------------------------------------------------
// Fused mean-pool + output proj: out = gelu(BN(mean_n(H1) @ W2 + b2)).
// ---------------------------------------------------------------------------
__global__ __launch_bounds__(256) void pf_kernel(
        const bf16_t* __restrict__ H1, const float* __restrict__ W2,
        const float* __restrict__ b2, const float* __restrict__ g2,
        const float* __restrict__ be2, const float* __restrict__ m2,
        const float* __restrict__ v2, float* __restrict__ out) {
    __shared__ float pl[HID];
    const int b = blockIdx.x, f = threadIdx.x;
    float s = 0.f;
    for (int n = 0; n < NNODES; ++n)
        s += (float)H1[((size_t)n * BATCH + b) * HID + f];
    pl[f] = s * (1.0f / (float)NNODES);
    __syncthreads();
    float acc = 0.f;
    for (int k = 0; k < HID; ++k) acc += pl[k] * W2[(size_t)k * HID + f];
    acc += b2[f];
    const float scale = g2[f] * rsqrtf(v2[f] + EPS_BN);
    acc = (acc - m2[f]) * scale + be2[f];
    out[b * HID + f] = gelu_f(acc);
}

// ---------------------------------------------------------------------------
extern "C" void kernel_launch(void* const* d_in, const int* in_sizes, int n_in,
                              void* d_out, int out_size, void* d_ws, size_t ws_size,
                              hipStream_t stream) {
    const float* x    = (const float*)d_in[0];
    const int*   ei   = (const int*)d_in[1];
    const float* W1   = (const float*)d_in[2];
    const float* b1   = (const float*)d_in[3];
    const float* g1   = (const float*)d_in[4];
    const float* be1  = (const float*)d_in[5];
    const float* m1   = (const float*)d_in[6];
    const float* v1   = (const float*)d_in[7];
    const float* Wl0  = (const float*)d_in[8];
    const float* bl0  = (const float*)d_in[9];
    const float* Wr0  = (const float*)d_in[10];
    const float* br0  = (const float*)d_in[11];
    const float* att0 = (const float*)d_in[12];
    const float* bo0  = (const float*)d_in[13];
    const float* Wl1  = (const float*)d_in[14];
    const float* bl1  = (const float*)d_in[15];
    const float* Wr1  = (const float*)d_in[16];
    const float* br1  = (const float*)d_in[17];
    const float* att1 = (const float*)d_in[18];
    const float* bo1  = (const float*)d_in[19];
    const float* W2   = (const float*)d_in[20];
    const float* b2   = (const float*)d_in[21];
    const float* g2   = (const float*)d_in[22];
    const float* be2  = (const float*)d_in[23];
    const float* m2   = (const float*)d_in[24];
    const float* v2   = (const float*)d_in[25];

    char* ws = (char*)d_ws;
    const int M = BATCH * NNODES;                        // 16384
    const size_t SZ_BF = (size_t)M * HID * sizeof(bf16_t);   // 8 MB

    int*    noff = (int*)ws;                ws += 2048;
    int*    csrc = (int*)ws;                ws += 32768;
    bf16_t* W1t  = (bf16_t*)ws;             ws += 256 * 768 * 2;
    bf16_t* Wl0t = (bf16_t*)ws;             ws += 256 * 256 * 2;
    bf16_t* Wr0t = (bf16_t*)ws;             ws += 256 * 256 * 2;
    bf16_t* Wl1t = (bf16_t*)ws;             ws += 256 * 256 * 2;
    bf16_t* Wr1t = (bf16_t*)ws;             ws += 256 * 256 * 2;
    bf16_t* H    = (bf16_t*)ws;             ws += SZ_BF;   // node_proj out / edge1 out
    bf16_t* H2   = (bf16_t*)ws;             ws += SZ_BF;   // edge0 out
    bf16_t* XL   = (bf16_t*)ws;             ws += SZ_BF;   // lin_l out
    bf16_t* XR   = (bf16_t*)ws;             ws += SZ_BF;   // lin_r out

    prep_kernel<<<449, 256, 0, stream>>>(ei, W1, Wl0, Wr0, Wl1, Wr1,
                                         noff, csrc, W1t, Wl0t, Wr0t, Wl1t, Wr1t);

    // node_proj: H = gelu(BN(x @ W1 + b1)), batch-major A -> node-major C
    gemm_kernel<1, 0, 1, 1><<<dim3(1, 128), 256, 0, stream>>>(
        x, W1t, nullptr, H, nullptr, 768, b1, nullptr, g1, be1, m1, v1);

    // layer 0: XL = H@Wl0+bl0, XR = H@Wr0+br0 (both bf16)
    gemm_kernel<0, 1, 0, 0><<<dim3(2, 128), 256, 0, stream>>>(
        H, Wl0t, Wr0t, XL, XR, 256, bl0, br0, nullptr, nullptr, nullptr, nullptr);
    edge_kernel<<<NNODES * 8, 256, 0, stream>>>(XL, XR, att0, bo0, noff, csrc, H2);

    // layer 1
    gemm_kernel<0, 1, 0, 0><<<dim3(2, 128), 256, 0, stream>>>(
        H2, Wl1t, Wr1t, XL, XR, 256, bl1, br1, nullptr, nullptr, nullptr, nullptr);
    edge_kernel<<<NNODES * 8, 256, 0, stream>>>(XL, XR, att1, bo1, noff, csrc, H);

    pf_kernel<<<BATCH, 256, 0, stream>>>(H, W2, b2, g2, be2, m2, v2, (float*)d_out);
}

// Round 8
// 321.687 us; speedup vs baseline: 1.0171x; 1.0171x over previous
//
#include <hip/hip_runtime.h>
#include <hip/hip_bf16.h>
#include <math.h>

// Problem constants (from reference)
#define BATCH   64
#define NNODES  256
#define HID     256
#define HEADS   4
#define CDIM    64
#define NEDGES  8192
#define NEG_SLOPE 0.2f
#define EPS_BN 1e-5f

// All intermediate activations use NODE-MAJOR layout: row = node*64 + batch.

typedef __bf16 bf16_t;
typedef __bf16 bf16x8 __attribute__((ext_vector_type(8)));
typedef float  f32x4  __attribute__((ext_vector_type(4)));

__device__ __forceinline__ float gelu_f(float x) {
    return 0.5f * x * (1.0f + erff(x * 0.70710678118654752440f));
}

// LDS bank swizzle for 16B chunks: rows r,r+8 never alias; reads/writes land
// 8 lanes per 16B slot (the b128 minimum). Row stride = 4 chunks = 64 B.
#define SWZ(r, c) ((c) ^ ((r) & 3) ^ (((r) >> 2) & 3))

// ---------------------------------------------------------------------------
// Fused CSR build + weight transpose/bf16-convert. Grid 449 x 256 threads.
// ---------------------------------------------------------------------------
__global__ __launch_bounds__(256) void prep_kernel(
        const int* __restrict__ ei,
        const float* __restrict__ W1, const float* __restrict__ Wa,
        const float* __restrict__ Wb, const float* __restrict__ Wc,
        const float* __restrict__ Wd,
        int* __restrict__ noff, int* __restrict__ csrc,
        bf16_t* __restrict__ T1, bf16_t* __restrict__ Ta,
        bf16_t* __restrict__ Tb, bf16_t* __restrict__ Tc,
        bf16_t* __restrict__ Td) {
    const int bx = blockIdx.x;
    const int tid = threadIdx.x;
    if (bx == 448) {
        __shared__ int cnt[NNODES];
        __shared__ int off_s[NNODES + 1];
        cnt[tid] = 0;
        __syncthreads();
        for (int e = tid; e < NEDGES; e += 256) atomicAdd(&cnt[ei[NEDGES + e]], 1);
        __syncthreads();
        if (tid == 0) {
            int s = 0;
            for (int i = 0; i < NNODES; ++i) { off_s[i] = s; s += cnt[i]; }
            off_s[NNODES] = s;
        }
        __syncthreads();
        cnt[tid] = off_s[tid];
        noff[tid] = off_s[tid];
        if (tid == 0) noff[NNODES] = off_s[NNODES];
        __syncthreads();
        for (int e = tid; e < NEDGES; e += 256) {
            int d = ei[NEDGES + e];
            int p = atomicAdd(&cnt[d], 1);
            csrc[p] = ei[e];
        }
        return;
    }
    __shared__ float tile[32][33];
    const float* in; bf16_t* out; int K, t;
    if (bx < 192) { in = W1; out = T1; K = 768; t = bx; }
    else {
        int r = bx - 192, mid = r >> 6; t = r & 63; K = 256;
        if (mid == 0) { in = Wa; out = Ta; }
        else if (mid == 1) { in = Wb; out = Tb; }
        else if (mid == 2) { in = Wc; out = Tc; }
        else { in = Wd; out = Td; }
    }
    const int kt = t >> 3, nt = t & 7;
    const int k0 = kt * 32, n0 = nt * 32;
    const int x = tid & 31, y = tid >> 5;
    #pragma unroll
    for (int j = 0; j < 4; ++j)
        tile[y + j * 8][x] = in[(size_t)(k0 + y + j * 8) * 256 + n0 + x];
    __syncthreads();
    #pragma unroll
    for (int j = 0; j < 4; ++j)
        out[(size_t)(n0 + y + j * 8) * K + k0 + x] = (bf16_t)tile[x][y + j * 8];
}

// ---------------------------------------------------------------------------
// MFMA bf16 GEMM, full-width, thin tiles: C[M x 256] = A[M x K] @ B[K x 256].
// Tile 32(M) x 256(N), BK=32; A fetched from HBM exactly once (rows split
// by block). 4 waves side-by-side in N: wave = 32 rows x 64 cols
// (2 m-frags x 4 n-frags, 8 acc). 8 MFMA : 6 ds_read_b128 per wave-K-iter.
// LDS 18 KB -> up to 4 blocks/CU with __launch_bounds__(256,4).
// PERM: A row = (r%64)*256+r/64 (batch-major input -> node-major output).
// DUAL: blockIdx.x = 0 -> (Bt0,C0,bias0), 1 -> (Bt1,C1,bias1).
// ---------------------------------------------------------------------------
template<int A_F32, int DUAL, int EPI_BN, int PERM>
__global__ __launch_bounds__(256, 4) void gemm_kernel(
        const void* __restrict__ Ap,
        const bf16_t* __restrict__ Bt0, const bf16_t* __restrict__ Bt1,
        bf16_t* __restrict__ C0p, bf16_t* __restrict__ C1p, int K,
        const float* __restrict__ bias0, const float* __restrict__ bias1,
        const float* __restrict__ g, const float* __restrict__ be,
        const float* __restrict__ mu, const float* __restrict__ var) {
    __shared__ bf16_t As[32 * 32];    // [32 rows][4 chunks of 8] swizzled, 2 KB
    __shared__ bf16_t Bs[256 * 32];   // [256 n ][4 chunks of 8] swizzled, 16 KB
    const int tid  = threadIdx.x;
    const int lane = tid & 63;
    const int wv   = tid >> 6;          // wave = N-quarter
    const int mblk = blockIdx.y * 32;
    const bool second = DUAL && (blockIdx.x == 1);
    const bf16_t* Bt = second ? Bt1 : Bt0;
    bf16_t* Cp = second ? C1p : C0p;
    const float* bias = second ? bias1 : bias0;

    f32x4 acc[2][4];
    #pragma unroll
    for (int f = 0; f < 2; ++f)
        #pragma unroll
        for (int t = 0; t < 4; ++t) acc[f][t] = (f32x4){0.f, 0.f, 0.f, 0.f};

    const int arow = tid >> 2;          // 0..63 (only tid<128 stages A)
    const int achk = tid & 3;
    const int gr   = mblk + arow;
    const int arr  = PERM ? ((gr & 63) * 256 + (gr >> 6)) : gr;
    const int fm   = lane & 15, q = lane >> 4;

    for (int k0 = 0; k0 < K; k0 += 32) {
        if (tid < 128) {
            bf16x8 v;
            if (A_F32) {
                const float* ap = (const float*)Ap + (size_t)arr * K + k0 + achk * 8;
                f32x4 a0 = *(const f32x4*)ap;
                f32x4 a1 = *(const f32x4*)(ap + 4);
                #pragma unroll
                for (int j = 0; j < 4; ++j) { v[j] = (bf16_t)a0[j]; v[4 + j] = (bf16_t)a1[j]; }
            } else {
                v = *(const bf16x8*)((const bf16_t*)Ap + (size_t)arr * K + k0 + achk * 8);
            }
            *(bf16x8*)(&As[(arow * 4 + SWZ(arow, achk)) * 8]) = v;
        }
        {
            const bf16_t* bp = Bt + (size_t)tid * K + k0;
            bf16x8 b0 = *(const bf16x8*)bp;
            bf16x8 b1 = *(const bf16x8*)(bp + 8);
            bf16x8 b2 = *(const bf16x8*)(bp + 16);
            bf16x8 b3 = *(const bf16x8*)(bp + 24);
            *(bf16x8*)(&Bs[(tid * 4 + SWZ(tid, 0)) * 8]) = b0;
            *(bf16x8*)(&Bs[(tid * 4 + SWZ(tid, 1)) * 8]) = b1;
            *(bf16x8*)(&Bs[(tid * 4 + SWZ(tid, 2)) * 8]) = b2;
            *(bf16x8*)(&Bs[(tid * 4 + SWZ(tid, 3)) * 8]) = b3;
        }
        __syncthreads();

        bf16x8 af[2], bfv[4];
        #pragma unroll
        for (int f = 0; f < 2; ++f) {
            const int r = f * 16 + fm;
            af[f] = *(const bf16x8*)(&As[(r * 4 + SWZ(r, q)) * 8]);
        }
        #pragma unroll
        for (int t = 0; t < 4; ++t) {
            const int n = wv * 64 + t * 16 + fm;
            bfv[t] = *(const bf16x8*)(&Bs[(n * 4 + SWZ(n, q)) * 8]);
        }
        #pragma unroll
        for (int f = 0; f < 2; ++f)
            #pragma unroll
            for (int t = 0; t < 4; ++t)
                acc[f][t] = __builtin_amdgcn_mfma_f32_16x16x32_bf16(
                    af[f], bfv[t], acc[f][t], 0, 0, 0);
        __syncthreads();
    }

    const int quad = lane >> 4, cn = lane & 15;
    #pragma unroll
    for (int t = 0; t < 4; ++t) {
        const int n = wv * 64 + t * 16 + cn;
        const float bv = bias[n];
        float scale = 1.0f, shift = 0.0f;
        if (EPI_BN) {
            float s = g[n] * rsqrtf(var[n] + EPS_BN);
            scale = s;
            shift = be[n] - mu[n] * s;
        }
        #pragma unroll
        for (int f = 0; f < 2; ++f) {
            #pragma unroll
            for (int r = 0; r < 4; ++r) {
                const int m = mblk + f * 16 + quad * 4 + r;
                float val = acc[f][t][r] + bv;
                if (EPI_BN) val = gelu_f(val * scale + shift);
                Cp[(size_t)m * 256 + n] = (bf16_t)val;
            }
        }
    }
}

// ---------------------------------------------------------------------------
// GATv2 edge softmax + aggregate, node-major, XCD-swizzled, 2-chain ILP.
// ---------------------------------------------------------------------------
__global__ __launch_bounds__(256) void edge_kernel(
        const bf16_t* __restrict__ XL, const bf16_t* __restrict__ XR,
        const float* __restrict__ att, const float* __restrict__ bo,
        const int* __restrict__ noff, const int* __restrict__ csrc,
        bf16_t* __restrict__ Hout) {
    const int bid  = blockIdx.x;
    const int i    = bid >> 3;
    const int tid  = threadIdx.x;
    const int w    = tid >> 6;
    const int lane = tid & 63;
    const int bg   = lane >> 3;
    const int cg   = lane & 7;
    const int b    = (bid & 7) * 8 + bg;
    const int cbase = w * CDIM + cg * 8;
    const size_t orow = ((size_t)i * BATCH + b) * HID + cbase;
    const float* bor = bo + cbase;

    const int s0 = noff[i], s1 = noff[i + 1];
    if (s0 == s1) {
        bf16x8 ov;
        #pragma unroll
        for (int q = 0; q < 8; ++q) ov[q] = (bf16_t)gelu_f(bor[q]);
        *(bf16x8*)(Hout + orow) = ov;
        return;
    }

    float a6[8], a4[8], xi[8];
    {
        const float* ar = att + cbase;
        const bf16x8 xr = *(const bf16x8*)(XR + orow);
        #pragma unroll
        for (int q = 0; q < 8; ++q) {
            float a = ar[q];
            a6[q] = 0.6f * a; a4[q] = 0.4f * a;
            xi[q] = (float)xr[q];
        }
    }

    const bf16_t* XLb = XL + (size_t)b * HID + cbase;
    const size_t RSTR = (size_t)BATCH * HID;

    float mA = -1e30f, dA = 0.f, mB = -1e30f, dB = 0.f;
    float accA[8], accB[8];
    #pragma unroll
    for (int q = 0; q < 8; ++q) { accA[q] = 0.f; accB[q] = 0.f; }

    int jA = csrc[s0];
    int jB = csrc[(s0 + 1 < s1) ? s0 + 1 : s0];
    bf16x8 xA = *(const bf16x8*)(XLb + (size_t)jA * RSTR);
    bf16x8 xB = *(const bf16x8*)(XLb + (size_t)jB * RSTR);

    for (int e = s0; e < s1; e += 2) {
        const int nA = (e + 2 < s1) ? e + 2 : s0;
        const int nB = (e + 3 < s1) ? e + 3 : s0;
        const int jnA = csrc[nA], jnB = csrc[nB];
        const bf16x8 xnA = *(const bf16x8*)(XLb + (size_t)jnA * RSTR);
        const bf16x8 xnB = *(const bf16x8*)(XLb + (size_t)jnB * RSTR);

        float fA[8], fB[8];
        #pragma unroll
        for (int q = 0; q < 8; ++q) { fA[q] = (float)xA[q]; fB[q] = (float)xB[q]; }
        float pA = 0.f, pB = 0.f;
        #pragma unroll
        for (int q = 0; q < 8; ++q) {
            const float zA = xi[q] + fA[q];
            const float zB = xi[q] + fB[q];
            pA = fmaf(a6[q], zA, pA);
            pB = fmaf(a6[q], zB, pB);
            pA = fmaf(a4[q], __builtin_fabsf(zA), pA);
            pB = fmaf(a4[q], __builtin_fabsf(zB), pB);
        }
        pA += __shfl_xor(pA, 1, 64);  pB += __shfl_xor(pB, 1, 64);
        pA += __shfl_xor(pA, 2, 64);  pB += __shfl_xor(pB, 2, 64);
        pA += __shfl_xor(pA, 4, 64);  pB += __shfl_xor(pB, 4, 64);

        const float mnA = fmaxf(mA, pA);
        const float alA = __expf(mA - mnA);
        const float wA  = __expf(pA - mnA);
        const float vB  = (e + 1 < s1) ? 1.f : 0.f;
        const float mnB = fmaxf(mB, pB);
        const float alB = __expf(mB - mnB);
        const float wB  = __expf(pB - mnB) * vB;
        dA = dA * alA + wA;
        dB = dB * alB + wB;
        #pragma unroll
        for (int q = 0; q < 8; ++q) {
            accA[q] = fmaf(accA[q], alA, wA * fA[q]);
            accB[q] = fmaf(accB[q], alB, wB * fB[q]);
        }
        mA = mnA; mB = mnB;
        xA = xnA; xB = xnB;
    }

    const float mm = fmaxf(mA, mB);
    const float g1 = __expf(mA - mm);
    const float g2 = __expf(mB - mm);
    const float inv = 1.0f / (dA * g1 + dB * g2 + 1e-16f);
    bf16x8 ov;
    #pragma unroll
    for (int q = 0; q < 8; ++q) {
        const float o = (accA[q] * g1 + accB[q] * g2) * inv + bor[q];
        ov[q] = (bf16_t)gelu_f(o);
    }
    *(bf16x8*)(Hout + orow) = ov;
}

// ---------------------------------------------------------------------------
// Fused mean-pool + output proj: out = gelu(BN(mean_n(H1) @ W2 + b2)).
// ---------------------------------------------------------------------------
__global__ __launch_bounds__(256) void pf_kernel(
        const bf16_t* __restrict__ H1, const float* __restrict__ W2,
        const float* __restrict__ b2, const float* __restrict__ g2,
        const float* __restrict__ be2, const float* __restrict__ m2,
        const float* __restrict__ v2, float* __restrict__ out) {
    __shared__ float pl[HID];
    const int b = blockIdx.x, f = threadIdx.x;
    float s = 0.f;
    for (int n = 0; n < NNODES; ++n)
        s += (float)H1[((size_t)n * BATCH + b) * HID + f];
    pl[f] = s * (1.0f / (float)NNODES);
    __syncthreads();
    float acc = 0.f;
    for (int k = 0; k < HID; ++k) acc += pl[k] * W2[(size_t)k * HID + f];
    acc += b2[f];
    const float scale = g2[f] * rsqrtf(v2[f] + EPS_BN);
    acc = (acc - m2[f]) * scale + be2[f];
    out[b * HID + f] = gelu_f(acc);
}

// ---------------------------------------------------------------------------
extern "C" void kernel_launch(void* const* d_in, const int* in_sizes, int n_in,
                              void* d_out, int out_size, void* d_ws, size_t ws_size,
                              hipStream_t stream) {
    const float* x    = (const float*)d_in[0];
    const int*   ei   = (const int*)d_in[1];
    const float* W1   = (const float*)d_in[2];
    const float* b1   = (const float*)d_in[3];
    const float* g1   = (const float*)d_in[4];
    const float* be1  = (const float*)d_in[5];
    const float* m1   = (const float*)d_in[6];
    const float* v1   = (const float*)d_in[7];
    const float* Wl0  = (const float*)d_in[8];
    const float* bl0  = (const float*)d_in[9];
    const float* Wr0  = (const float*)d_in[10];
    const float* br0  = (const float*)d_in[11];
    const float* att0 = (const float*)d_in[12];
    const float* bo0  = (const float*)d_in[13];
    const float* Wl1  = (const float*)d_in[14];
    const float* bl1  = (const float*)d_in[15];
    const float* Wr1  = (const float*)d_in[16];
    const float* br1  = (const float*)d_in[17];
    const float* att1 = (const float*)d_in[18];
    const float* bo1  = (const float*)d_in[19];
    const float* W2   = (const float*)d_in[20];
    const float* b2   = (const float*)d_in[21];
    const float* g2   = (const float*)d_in[22];
    const float* be2  = (const float*)d_in[23];
    const float* m2   = (const float*)d_in[24];
    const float* v2   = (const float*)d_in[25];

    char* ws = (char*)d_ws;
    const int M = BATCH * NNODES;                        // 16384
    const size_t SZ_BF = (size_t)M * HID * sizeof(bf16_t);   // 8 MB

    int*    noff = (int*)ws;                ws += 2048;
    int*    csrc = (int*)ws;                ws += 32768;
    bf16_t* W1t  = (bf16_t*)ws;             ws += 256 * 768 * 2;
    bf16_t* Wl0t = (bf16_t*)ws;             ws += 256 * 256 * 2;
    bf16_t* Wr0t = (bf16_t*)ws;             ws += 256 * 256 * 2;
    bf16_t* Wl1t = (bf16_t*)ws;             ws += 256 * 256 * 2;
    bf16_t* Wr1t = (bf16_t*)ws;             ws += 256 * 256 * 2;
    bf16_t* H    = (bf16_t*)ws;             ws += SZ_BF;   // node_proj out / edge1 out
    bf16_t* H2   = (bf16_t*)ws;             ws += SZ_BF;   // edge0 out
    bf16_t* XL   = (bf16_t*)ws;             ws += SZ_BF;   // lin_l out
    bf16_t* XR   = (bf16_t*)ws;             ws += SZ_BF;   // lin_r out

    prep_kernel<<<449, 256, 0, stream>>>(ei, W1, Wl0, Wr0, Wl1, Wr1,
                                         noff, csrc, W1t, Wl0t, Wr0t, Wl1t, Wr1t);

    // node_proj: H = gelu(BN(x @ W1 + b1)), batch-major A -> node-major C
    gemm_kernel<1, 0, 1, 1><<<dim3(1, 512), 256, 0, stream>>>(
        x, W1t, nullptr, H, nullptr, 768, b1, nullptr, g1, be1, m1, v1);

    // layer 0: XL = H@Wl0+bl0, XR = H@Wr0+br0 (both bf16)
    gemm_kernel<0, 1, 0, 0><<<dim3(2, 512), 256, 0, stream>>>(
        H, Wl0t, Wr0t, XL, XR, 256, bl0, br0, nullptr, nullptr, nullptr, nullptr);
    edge_kernel<<<NNODES * 8, 256, 0, stream>>>(XL, XR, att0, bo0, noff, csrc, H2);

    // layer 1
    gemm_kernel<0, 1, 0, 0><<<dim3(2, 512), 256, 0, stream>>>(
        H2, Wl1t, Wr1t, XL, XR, 256, bl1, br1, nullptr, nullptr, nullptr, nullptr);
    edge_kernel<<<NNODES * 8, 256, 0, stream>>>(XL, XR, att1, bo1, noff, csrc, H);

    pf_kernel<<<BATCH, 256, 0, stream>>>(H, W2, b2, g2, be2, m2, v2, (float*)d_out);
}

// Round 9
// 297.122 us; speedup vs baseline: 1.1012x; 1.0827x over previous
//
#include <hip/hip_runtime.h>
#include <hip/hip_bf16.h>
#include <math.h>

// Problem constants (from reference)
#define BATCH   64
#define NNODES  256
#define HID     256
#define HEADS   4
#define CDIM    64
#define NEDGES  8192
#define NEG_SLOPE 0.2f
#define EPS_BN 1e-5f

// All intermediate activations use NODE-MAJOR layout: row = node*64 + batch.
// Weights are pre-packed into K-tile panels: [K/32][256 n][32 k] bf16, so a
// GEMM block stages each 16 KB B-panel with fully-coalesced sequential loads.

typedef __bf16 bf16_t;
typedef __bf16 bf16x8 __attribute__((ext_vector_type(8)));
typedef float  f32x4  __attribute__((ext_vector_type(4)));

__device__ __forceinline__ float gelu_f(float x) {
    return 0.5f * x * (1.0f + erff(x * 0.70710678118654752440f));
}

// LDS bank swizzle for 16B chunks. Bit4 term makes staging writes (rows
// r, r+16, r+32, r+48 per wave) conflict-free; frag reads stay 2-way (free).
#define SWZ(r, c) ((c) ^ ((r) & 3) ^ (((r) >> 2) & 3) ^ (((r) >> 4) & 3))

// ---------------------------------------------------------------------------
// Fused CSR build + weight panel-pack/bf16-convert. Grid 449 x 256 threads.
// Panel layout: T[(k>>5)*256*32 + n*32 + (k&31)] = bf16(W[k][n]).
// ---------------------------------------------------------------------------
__global__ __launch_bounds__(256) void prep_kernel(
        const int* __restrict__ ei,
        const float* __restrict__ W1, const float* __restrict__ Wa,
        const float* __restrict__ Wb, const float* __restrict__ Wc,
        const float* __restrict__ Wd,
        int* __restrict__ noff, int* __restrict__ csrc,
        bf16_t* __restrict__ T1, bf16_t* __restrict__ Ta,
        bf16_t* __restrict__ Tb, bf16_t* __restrict__ Tc,
        bf16_t* __restrict__ Td) {
    const int bx = blockIdx.x;
    const int tid = threadIdx.x;
    if (bx == 448) {
        __shared__ int cnt[NNODES];
        __shared__ int off_s[NNODES + 1];
        cnt[tid] = 0;
        __syncthreads();
        for (int e = tid; e < NEDGES; e += 256) atomicAdd(&cnt[ei[NEDGES + e]], 1);
        __syncthreads();
        if (tid == 0) {
            int s = 0;
            for (int i = 0; i < NNODES; ++i) { off_s[i] = s; s += cnt[i]; }
            off_s[NNODES] = s;
        }
        __syncthreads();
        cnt[tid] = off_s[tid];
        noff[tid] = off_s[tid];
        if (tid == 0) noff[NNODES] = off_s[NNODES];
        __syncthreads();
        for (int e = tid; e < NEDGES; e += 256) {
            int d = ei[NEDGES + e];
            int p = atomicAdd(&cnt[d], 1);
            csrc[p] = ei[e];
        }
        return;
    }
    __shared__ float tile[32][33];
    const float* in; bf16_t* out; int t;
    if (bx < 192) { in = W1; out = T1; t = bx; }
    else {
        int r = bx - 192, mid = r >> 6; t = r & 63;
        if (mid == 0) { in = Wa; out = Ta; }
        else if (mid == 1) { in = Wb; out = Tb; }
        else if (mid == 2) { in = Wc; out = Tc; }
        else { in = Wd; out = Td; }
    }
    const int kt = t >> 3, nt = t & 7;
    const int k0 = kt * 32, n0 = nt * 32;
    const int x = tid & 31, y = tid >> 5;
    #pragma unroll
    for (int j = 0; j < 4; ++j)
        tile[y + j * 8][x] = in[(size_t)(k0 + y + j * 8) * 256 + n0 + x];
    __syncthreads();
    // panel write: out[(kt*256 + n)*32 + kk], kk = x -> coalesced across lanes
    #pragma unroll
    for (int j = 0; j < 4; ++j) {
        const int n = n0 + y + j * 8;
        out[((size_t)kt * 256 + n) * 32 + x] = (bf16_t)tile[x][y + j * 8];
    }
}

// ---------------------------------------------------------------------------
// MFMA bf16 GEMM, full-width, thin tiles: C[M x 256] = A[M x K] @ B[K x 256].
// Tile 32(M) x 256(N), BK=32; A fetched from HBM exactly once. B staged from
// contiguous 16 KB panels (4 coalesced 1KB wave-loads). 4 waves in N: wave =
// 32 rows x 64 cols (2 m-frags x 4 n-frags). XOR-swizzled LDS, conflict-free.
// PERM: A row = (r%64)*256+r/64. DUAL: blockIdx.x selects (Bt,C,bias) pair.
// ---------------------------------------------------------------------------
template<int A_F32, int DUAL, int EPI_BN, int PERM>
__global__ __launch_bounds__(256, 4) void gemm_kernel(
        const void* __restrict__ Ap,
        const bf16_t* __restrict__ Bt0, const bf16_t* __restrict__ Bt1,
        bf16_t* __restrict__ C0p, bf16_t* __restrict__ C1p, int K,
        const float* __restrict__ bias0, const float* __restrict__ bias1,
        const float* __restrict__ g, const float* __restrict__ be,
        const float* __restrict__ mu, const float* __restrict__ var) {
    __shared__ bf16_t As[32 * 32];    // [32 rows][4 chunks of 8] swizzled, 2 KB
    __shared__ bf16_t Bs[256 * 32];   // [256 n ][4 chunks of 8] swizzled, 16 KB
    const int tid  = threadIdx.x;
    const int lane = tid & 63;
    const int wv   = tid >> 6;          // wave = N-quarter
    const int mblk = blockIdx.y * 32;
    const bool second = DUAL && (blockIdx.x == 1);
    const bf16_t* Bt = second ? Bt1 : Bt0;
    bf16_t* Cp = second ? C1p : C0p;
    const float* bias = second ? bias1 : bias0;

    f32x4 acc[2][4];
    #pragma unroll
    for (int f = 0; f < 2; ++f)
        #pragma unroll
        for (int t = 0; t < 4; ++t) acc[f][t] = (f32x4){0.f, 0.f, 0.f, 0.f};

    const int arow = tid >> 2;          // 0..31 for tid<128
    const int achk = tid & 3;
    const int gr   = mblk + arow;
    const int arr  = PERM ? ((gr & 63) * 256 + (gr >> 6)) : gr;
    const int fm   = lane & 15, q = lane >> 4;

    for (int k0 = 0; k0 < K; k0 += 32) {
        if (tid < 128) {
            bf16x8 v;
            if (A_F32) {
                const float* ap = (const float*)Ap + (size_t)arr * K + k0 + achk * 8;
                f32x4 a0 = *(const f32x4*)ap;
                f32x4 a1 = *(const f32x4*)(ap + 4);
                #pragma unroll
                for (int j = 0; j < 4; ++j) { v[j] = (bf16_t)a0[j]; v[4 + j] = (bf16_t)a1[j]; }
            } else {
                v = *(const bf16x8*)((const bf16_t*)Ap + (size_t)arr * K + k0 + achk * 8);
            }
            *(bf16x8*)(&As[(arow * 4 + SWZ(arow, achk)) * 8]) = v;
        }
        {
            // B panel: contiguous 16 KB; chunk f = c*256+tid -> n=f>>2, kc=f&3
            const bf16_t* panel = Bt + (size_t)(k0 >> 5) * (256 * 32);
            #pragma unroll
            for (int c = 0; c < 4; ++c) {
                const int f = c * 256 + tid;
                const bf16x8 bv = *(const bf16x8*)(panel + (size_t)f * 8);
                const int n = f >> 2, kc = f & 3;
                *(bf16x8*)(&Bs[(n * 4 + SWZ(n, kc)) * 8]) = bv;
            }
        }
        __syncthreads();

        bf16x8 af[2], bfv[4];
        #pragma unroll
        for (int f = 0; f < 2; ++f) {
            const int r = f * 16 + fm;
            af[f] = *(const bf16x8*)(&As[(r * 4 + SWZ(r, q)) * 8]);
        }
        #pragma unroll
        for (int t = 0; t < 4; ++t) {
            const int n = wv * 64 + t * 16 + fm;
            bfv[t] = *(const bf16x8*)(&Bs[(n * 4 + SWZ(n, q)) * 8]);
        }
        #pragma unroll
        for (int f = 0; f < 2; ++f)
            #pragma unroll
            for (int t = 0; t < 4; ++t)
                acc[f][t] = __builtin_amdgcn_mfma_f32_16x16x32_bf16(
                    af[f], bfv[t], acc[f][t], 0, 0, 0);
        __syncthreads();
    }

    const int quad = lane >> 4, cn = lane & 15;
    #pragma unroll
    for (int t = 0; t < 4; ++t) {
        const int n = wv * 64 + t * 16 + cn;
        const float bv = bias[n];
        float scale = 1.0f, shift = 0.0f;
        if (EPI_BN) {
            float s = g[n] * rsqrtf(var[n] + EPS_BN);
            scale = s;
            shift = be[n] - mu[n] * s;
        }
        #pragma unroll
        for (int f = 0; f < 2; ++f) {
            #pragma unroll
            for (int r = 0; r < 4; ++r) {
                const int m = mblk + f * 16 + quad * 4 + r;
                float val = acc[f][t][r] + bv;
                if (EPI_BN) val = gelu_f(val * scale + shift);
                Cp[(size_t)m * 256 + n] = (bf16_t)val;
            }
        }
    }
}

// ---------------------------------------------------------------------------
// GATv2 edge softmax + aggregate, node-major, XCD-swizzled, 2-chain ILP.
// ---------------------------------------------------------------------------
__global__ __launch_bounds__(256) void edge_kernel(
        const bf16_t* __restrict__ XL, const bf16_t* __restrict__ XR,
        const float* __restrict__ att, const float* __restrict__ bo,
        const int* __restrict__ noff, const int* __restrict__ csrc,
        bf16_t* __restrict__ Hout) {
    const int bid  = blockIdx.x;
    const int i    = bid >> 3;
    const int tid  = threadIdx.x;
    const int w    = tid >> 6;
    const int lane = tid & 63;
    const int bg   = lane >> 3;
    const int cg   = lane & 7;
    const int b    = (bid & 7) * 8 + bg;
    const int cbase = w * CDIM + cg * 8;
    const size_t orow = ((size_t)i * BATCH + b) * HID + cbase;
    const float* bor = bo + cbase;

    const int s0 = noff[i], s1 = noff[i + 1];
    if (s0 == s1) {
        bf16x8 ov;
        #pragma unroll
        for (int q = 0; q < 8; ++q) ov[q] = (bf16_t)gelu_f(bor[q]);
        *(bf16x8*)(Hout + orow) = ov;
        return;
    }

    float a6[8], a4[8], xi[8];
    {
        const float* ar = att + cbase;
        const bf16x8 xr = *(const bf16x8*)(XR + orow);
        #pragma unroll
        for (int q = 0; q < 8; ++q) {
            float a = ar[q];
            a6[q] = 0.6f * a; a4[q] = 0.4f * a;
            xi[q] = (float)xr[q];
        }
    }

    const bf16_t* XLb = XL + (size_t)b * HID + cbase;
    const size_t RSTR = (size_t)BATCH * HID;

    float mA = -1e30f, dA = 0.f, mB = -1e30f, dB = 0.f;
    float accA[8], accB[8];
    #pragma unroll
    for (int q = 0; q < 8; ++q) { accA[q] = 0.f; accB[q] = 0.f; }

    int jA = csrc[s0];
    int jB = csrc[(s0 + 1 < s1) ? s0 + 1 : s0];
    bf16x8 xA = *(const bf16x8*)(XLb + (size_t)jA * RSTR);
    bf16x8 xB = *(const bf16x8*)(XLb + (size_t)jB * RSTR);

    for (int e = s0; e < s1; e += 2) {
        const int nA = (e + 2 < s1) ? e + 2 : s0;
        const int nB = (e + 3 < s1) ? e + 3 : s0;
        const int jnA = csrc[nA], jnB = csrc[nB];
        const bf16x8 xnA = *(const bf16x8*)(XLb + (size_t)jnA * RSTR);
        const bf16x8 xnB = *(const bf16x8*)(XLb + (size_t)jnB * RSTR);

        float fA[8], fB[8];
        #pragma unroll
        for (int q = 0; q < 8; ++q) { fA[q] = (float)xA[q]; fB[q] = (float)xB[q]; }
        float pA = 0.f, pB = 0.f;
        #pragma unroll
        for (int q = 0; q < 8; ++q) {
            const float zA = xi[q] + fA[q];
            const float zB = xi[q] + fB[q];
            pA = fmaf(a6[q], zA, pA);
            pB = fmaf(a6[q], zB, pB);
            pA = fmaf(a4[q], __builtin_fabsf(zA), pA);
            pB = fmaf(a4[q], __builtin_fabsf(zB), pB);
        }
        pA += __shfl_xor(pA, 1, 64);  pB += __shfl_xor(pB, 1, 64);
        pA += __shfl_xor(pA, 2, 64);  pB += __shfl_xor(pB, 2, 64);
        pA += __shfl_xor(pA, 4, 64);  pB += __shfl_xor(pB, 4, 64);

        const float mnA = fmaxf(mA, pA);
        const float alA = __expf(mA - mnA);
        const float wA  = __expf(pA - mnA);
        const float vB  = (e + 1 < s1) ? 1.f : 0.f;
        const float mnB = fmaxf(mB, pB);
        const float alB = __expf(mB - mnB);
        const float wB  = __expf(pB - mnB) * vB;
        dA = dA * alA + wA;
        dB = dB * alB + wB;
        #pragma unroll
        for (int q = 0; q < 8; ++q) {
            accA[q] = fmaf(accA[q], alA, wA * fA[q]);
            accB[q] = fmaf(accB[q], alB, wB * fB[q]);
        }
        mA = mnA; mB = mnB;
        xA = xnA; xB = xnB;
    }

    const float mm = fmaxf(mA, mB);
    const float g1 = __expf(mA - mm);
    const float g2 = __expf(mB - mm);
    const float inv = 1.0f / (dA * g1 + dB * g2 + 1e-16f);
    bf16x8 ov;
    #pragma unroll
    for (int q = 0; q < 8; ++q) {
        const float o = (accA[q] * g1 + accB[q] * g2) * inv + bor[q];
        ov[q] = (bf16_t)gelu_f(o);
    }
    *(bf16x8*)(Hout + orow) = ov;
}

// ---------------------------------------------------------------------------
// Fused mean-pool + output proj: out = gelu(BN(mean_n(H1) @ W2 + b2)).
// ---------------------------------------------------------------------------
__global__ __launch_bounds__(256) void pf_kernel(
        const bf16_t* __restrict__ H1, const float* __restrict__ W2,
        const float* __restrict__ b2, const float* __restrict__ g2,
        const float* __restrict__ be2, const float* __restrict__ m2,
        const float* __restrict__ v2, float* __restrict__ out) {
    __shared__ float pl[HID];
    const int b = blockIdx.x, f = threadIdx.x;
    float s = 0.f;
    for (int n = 0; n < NNODES; ++n)
        s += (float)H1[((size_t)n * BATCH + b) * HID + f];
    pl[f] = s * (1.0f / (float)NNODES);
    __syncthreads();
    float acc = 0.f;
    for (int k = 0; k < HID; ++k) acc += pl[k] * W2[(size_t)k * HID + f];
    acc += b2[f];
    const float scale = g2[f] * rsqrtf(v2[f] + EPS_BN);
    acc = (acc - m2[f]) * scale + be2[f];
    out[b * HID + f] = gelu_f(acc);
}

// ---------------------------------------------------------------------------
extern "C" void kernel_launch(void* const* d_in, const int* in_sizes, int n_in,
                              void* d_out, int out_size, void* d_ws, size_t ws_size,
                              hipStream_t stream) {
    const float* x    = (const float*)d_in[0];
    const int*   ei   = (const int*)d_in[1];
    const float* W1   = (const float*)d_in[2];
    const float* b1   = (const float*)d_in[3];
    const float* g1   = (const float*)d_in[4];
    const float* be1  = (const float*)d_in[5];
    const float* m1   = (const float*)d_in[6];
    const float* v1   = (const float*)d_in[7];
    const float* Wl0  = (const float*)d_in[8];
    const float* bl0  = (const float*)d_in[9];
    const float* Wr0  = (const float*)d_in[10];
    const float* br0  = (const float*)d_in[11];
    const float* att0 = (const float*)d_in[12];
    const float* bo0  = (const float*)d_in[13];
    const float* Wl1  = (const float*)d_in[14];
    const float* bl1  = (const float*)d_in[15];
    const float* Wr1  = (const float*)d_in[16];
    const float* br1  = (const float*)d_in[17];
    const float* att1 = (const float*)d_in[18];
    const float* bo1  = (const float*)d_in[19];
    const float* W2   = (const float*)d_in[20];
    const float* b2   = (const float*)d_in[21];
    const float* g2   = (const float*)d_in[22];
    const float* be2  = (const float*)d_in[23];
    const float* m2   = (const float*)d_in[24];
    const float* v2   = (const float*)d_in[25];

    char* ws = (char*)d_ws;
    const int M = BATCH * NNODES;                        // 16384
    const size_t SZ_BF = (size_t)M * HID * sizeof(bf16_t);   // 8 MB

    int*    noff = (int*)ws;                ws += 2048;
    int*    csrc = (int*)ws;                ws += 32768;
    bf16_t* W1t  = (bf16_t*)ws;             ws += 256 * 768 * 2;
    bf16_t* Wl0t = (bf16_t*)ws;             ws += 256 * 256 * 2;
    bf16_t* Wr0t = (bf16_t*)ws;             ws += 256 * 256 * 2;
    bf16_t* Wl1t = (bf16_t*)ws;             ws += 256 * 256 * 2;
    bf16_t* Wr1t = (bf16_t*)ws;             ws += 256 * 256 * 2;
    bf16_t* H    = (bf16_t*)ws;             ws += SZ_BF;   // node_proj out / edge1 out
    bf16_t* H2   = (bf16_t*)ws;             ws += SZ_BF;   // edge0 out
    bf16_t* XL   = (bf16_t*)ws;             ws += SZ_BF;   // lin_l out
    bf16_t* XR   = (bf16_t*)ws;             ws += SZ_BF;   // lin_r out

    prep_kernel<<<449, 256, 0, stream>>>(ei, W1, Wl0, Wr0, Wl1, Wr1,
                                         noff, csrc, W1t, Wl0t, Wr0t, Wl1t, Wr1t);

    // node_proj: H = gelu(BN(x @ W1 + b1)), batch-major A -> node-major C
    gemm_kernel<1, 0, 1, 1><<<dim3(1, 512), 256, 0, stream>>>(
        x, W1t, nullptr, H, nullptr, 768, b1, nullptr, g1, be1, m1, v1);

    // layer 0: XL = H@Wl0+bl0, XR = H@Wr0+br0 (both bf16)
    gemm_kernel<0, 1, 0, 0><<<dim3(2, 512), 256, 0, stream>>>(
        H, Wl0t, Wr0t, XL, XR, 256, bl0, br0, nullptr, nullptr, nullptr, nullptr);
    edge_kernel<<<NNODES * 8, 256, 0, stream>>>(XL, XR, att0, bo0, noff, csrc, H2);

    // layer 1
    gemm_kernel<0, 1, 0, 0><<<dim3(2, 512), 256, 0, stream>>>(
        H2, Wl1t, Wr1t, XL, XR, 256, bl1, br1, nullptr, nullptr, nullptr, nullptr);
    edge_kernel<<<NNODES * 8, 256, 0, stream>>>(XL, XR, att1, bo1, noff, csrc, H);

    pf_kernel<<<BATCH, 256, 0, stream>>>(H, W2, b2, g2, be2, m2, v2, (float*)d_out);
}

// Round 10
// 278.847 us; speedup vs baseline: 1.1734x; 1.0655x over previous
//
#include <hip/hip_runtime.h>
#include <hip/hip_bf16.h>
#include <math.h>

// Problem constants (from reference)
#define BATCH   64
#define NNODES  256
#define HID     256
#define HEADS   4
#define CDIM    64
#define NEDGES  8192
#define NEG_SLOPE 0.2f
#define EPS_BN 1e-5f

// All intermediate activations use NODE-MAJOR layout: row = node*64 + batch.
// Weights pre-packed into K-tile panels: [K/32][256 n][32 k] bf16.

typedef __bf16 bf16_t;
typedef __bf16 bf16x8 __attribute__((ext_vector_type(8)));
typedef float  f32x4  __attribute__((ext_vector_type(4)));

__device__ __forceinline__ float gelu_f(float x) {
    return 0.5f * x * (1.0f + erff(x * 0.70710678118654752440f));
}

// LDS bank swizzle for 16B chunks.
#define SWZ(r, c) ((c) ^ ((r) & 3) ^ (((r) >> 2) & 3) ^ (((r) >> 4) & 3))

// ---------------------------------------------------------------------------
// Fused CSR build + weight panel-pack/bf16-convert. Grid 449 x 256 threads.
// CSR prefix scan is parallel (Hillis-Steele) — no serial tid-0 loop.
// ---------------------------------------------------------------------------
__global__ __launch_bounds__(256) void prep_kernel(
        const int* __restrict__ ei,
        const float* __restrict__ W1, const float* __restrict__ Wa,
        const float* __restrict__ Wb, const float* __restrict__ Wc,
        const float* __restrict__ Wd,
        int* __restrict__ noff, int* __restrict__ csrc,
        bf16_t* __restrict__ T1, bf16_t* __restrict__ Ta,
        bf16_t* __restrict__ Tb, bf16_t* __restrict__ Tc,
        bf16_t* __restrict__ Td) {
    const int bx = blockIdx.x;
    const int tid = threadIdx.x;
    if (bx == 448) {
        __shared__ int cnt[NNODES];
        __shared__ int sc[NNODES];
        cnt[tid] = 0;
        __syncthreads();
        for (int e = tid; e < NEDGES; e += 256) atomicAdd(&cnt[ei[NEDGES + e]], 1);
        __syncthreads();
        sc[tid] = cnt[tid];
        __syncthreads();
        #pragma unroll
        for (int ofs = 1; ofs < 256; ofs <<= 1) {
            const int t = (tid >= ofs) ? sc[tid - ofs] : 0;
            __syncthreads();
            sc[tid] += t;
            __syncthreads();
        }
        const int excl = sc[tid] - cnt[tid];
        noff[tid] = excl;
        if (tid == 255) noff[NNODES] = sc[255];
        cnt[tid] = excl;          // reuse as cursor
        __syncthreads();
        for (int e = tid; e < NEDGES; e += 256) {
            int d = ei[NEDGES + e];
            int p = atomicAdd(&cnt[d], 1);
            csrc[p] = ei[e];
        }
        return;
    }
    __shared__ float tile[32][33];
    const float* in; bf16_t* out; int t;
    if (bx < 192) { in = W1; out = T1; t = bx; }
    else {
        int r = bx - 192, mid = r >> 6; t = r & 63;
        if (mid == 0) { in = Wa; out = Ta; }
        else if (mid == 1) { in = Wb; out = Tb; }
        else if (mid == 2) { in = Wc; out = Tc; }
        else { in = Wd; out = Td; }
    }
    const int kt = t >> 3, nt = t & 7;
    const int k0 = kt * 32, n0 = nt * 32;
    const int x = tid & 31, y = tid >> 5;
    #pragma unroll
    for (int j = 0; j < 4; ++j)
        tile[y + j * 8][x] = in[(size_t)(k0 + y + j * 8) * 256 + n0 + x];
    __syncthreads();
    #pragma unroll
    for (int j = 0; j < 4; ++j) {
        const int n = n0 + y + j * 8;
        out[((size_t)kt * 256 + n) * 32 + x] = (bf16_t)tile[x][y + j * 8];
    }
}

// ---------------------------------------------------------------------------
// MFMA bf16 GEMM, single-barrier pipelined K-loop, double-buffered LDS.
// Tile 32(M) x 256(N), BK=32. Per K-tile: write LDS (dbuf) -> ONE barrier ->
// issue next tile's global loads (overlap MFMA) -> 8 MFMA/wave.
// PERM: A row = (r%64)*256+r/64. DUAL: blockIdx.x selects (Bt,C,bias) pair.
// ---------------------------------------------------------------------------
template<int A_F32, int DUAL, int EPI_BN, int PERM, int KTILES>
__global__ __launch_bounds__(256, 4) void gemm_kernel(
        const void* __restrict__ Ap,
        const bf16_t* __restrict__ Bt0, const bf16_t* __restrict__ Bt1,
        bf16_t* __restrict__ C0p, bf16_t* __restrict__ C1p,
        const float* __restrict__ bias0, const float* __restrict__ bias1,
        const float* __restrict__ g, const float* __restrict__ be,
        const float* __restrict__ mu, const float* __restrict__ var) {
    __shared__ bf16_t As[2][32 * 32];    // 2 x 2 KB, swizzled 16B chunks
    __shared__ bf16_t Bs[2][256 * 32];   // 2 x 16 KB
    const int K = KTILES * 32;
    const int tid  = threadIdx.x;
    const int lane = tid & 63;
    const int wv   = tid >> 6;
    const int mblk = blockIdx.y * 32;
    const bool second = DUAL && (blockIdx.x == 1);
    const bf16_t* Bt = second ? Bt1 : Bt0;
    bf16_t* Cp = second ? C1p : C0p;
    const float* bias = second ? bias1 : bias0;

    f32x4 acc[2][4];
    #pragma unroll
    for (int f = 0; f < 2; ++f)
        #pragma unroll
        for (int t = 0; t < 4; ++t) acc[f][t] = (f32x4){0.f, 0.f, 0.f, 0.f};

    const int arow = (tid & 127) >> 2;
    const int achk = tid & 3;
    const int gr   = mblk + arow;
    const int arr  = PERM ? ((gr & 63) * 256 + (gr >> 6)) : gr;
    const int fm   = lane & 15, q = lane >> 4;
    const int bn   = tid >> 2;           // B-stage n base (per c: +c*64)

    f32x4 a0, a1; bf16x8 aReg; bf16x8 bReg[4];

    // --- load tile 0 ---
    if (tid < 128) {
        if (A_F32) {
            const float* ap = (const float*)Ap + (size_t)arr * K + achk * 8;
            a0 = *(const f32x4*)ap; a1 = *(const f32x4*)(ap + 4);
        } else {
            aReg = *(const bf16x8*)((const bf16_t*)Ap + (size_t)arr * K + achk * 8);
        }
    }
    {
        const bf16_t* panel = Bt + (size_t)tid * 8;
        #pragma unroll
        for (int c = 0; c < 4; ++c) bReg[c] = *(const bf16x8*)(panel + c * 2048);
    }

    #pragma unroll
    for (int kt = 0; kt < KTILES; ++kt) {
        const int buf = kt & 1;
        // write staged regs -> LDS[buf]
        if (tid < 128) {
            bf16x8 v;
            if (A_F32) {
                #pragma unroll
                for (int j = 0; j < 4; ++j) { v[j] = (bf16_t)a0[j]; v[4 + j] = (bf16_t)a1[j]; }
            } else v = aReg;
            *(bf16x8*)(&As[buf][(arow * 4 + SWZ(arow, achk)) * 8]) = v;
        }
        #pragma unroll
        for (int c = 0; c < 4; ++c) {
            const int n = c * 64 + bn;
            *(bf16x8*)(&Bs[buf][(n * 4 + SWZ(n, achk)) * 8]) = bReg[c];
        }
        __syncthreads();
        // issue next tile's loads AFTER the barrier -> overlap with MFMA
        if (kt + 1 < KTILES) {
            const int k0 = (kt + 1) * 32;
            if (tid < 128) {
                if (A_F32) {
                    const float* ap = (const float*)Ap + (size_t)arr * K + k0 + achk * 8;
                    a0 = *(const f32x4*)ap; a1 = *(const f32x4*)(ap + 4);
                } else {
                    aReg = *(const bf16x8*)((const bf16_t*)Ap + (size_t)arr * K + k0 + achk * 8);
                }
            }
            const bf16_t* panel = Bt + (size_t)(kt + 1) * (256 * 32) + (size_t)tid * 8;
            #pragma unroll
            for (int c = 0; c < 4; ++c) bReg[c] = *(const bf16x8*)(panel + c * 2048);
        }
        // fragments + MFMA from LDS[buf]
        bf16x8 af[2], bfv[4];
        #pragma unroll
        for (int f = 0; f < 2; ++f) {
            const int r = f * 16 + fm;
            af[f] = *(const bf16x8*)(&As[buf][(r * 4 + SWZ(r, q)) * 8]);
        }
        #pragma unroll
        for (int t = 0; t < 4; ++t) {
            const int n = wv * 64 + t * 16 + fm;
            bfv[t] = *(const bf16x8*)(&Bs[buf][(n * 4 + SWZ(n, q)) * 8]);
        }
        #pragma unroll
        for (int f = 0; f < 2; ++f)
            #pragma unroll
            for (int t = 0; t < 4; ++t)
                acc[f][t] = __builtin_amdgcn_mfma_f32_16x16x32_bf16(
                    af[f], bfv[t], acc[f][t], 0, 0, 0);
    }

    const int quad = lane >> 4, cn = lane & 15;
    #pragma unroll
    for (int t = 0; t < 4; ++t) {
        const int n = wv * 64 + t * 16 + cn;
        const float bv = bias[n];
        float scale = 1.0f, shift = 0.0f;
        if (EPI_BN) {
            float s = g[n] * rsqrtf(var[n] + EPS_BN);
            scale = s;
            shift = be[n] - mu[n] * s;
        }
        #pragma unroll
        for (int f = 0; f < 2; ++f) {
            #pragma unroll
            for (int r = 0; r < 4; ++r) {
                const int m = mblk + f * 16 + quad * 4 + r;
                float val = acc[f][t][r] + bv;
                if (EPI_BN) val = gelu_f(val * scale + shift);
                Cp[(size_t)m * 256 + n] = (bf16_t)val;
            }
        }
    }
}

// ---------------------------------------------------------------------------
// GATv2 edge softmax + aggregate, node-major, XCD-swizzled, 2-chain ILP.
// ---------------------------------------------------------------------------
__global__ __launch_bounds__(256) void edge_kernel(
        const bf16_t* __restrict__ XL, const bf16_t* __restrict__ XR,
        const float* __restrict__ att, const float* __restrict__ bo,
        const int* __restrict__ noff, const int* __restrict__ csrc,
        bf16_t* __restrict__ Hout) {
    const int bid  = blockIdx.x;
    const int i    = bid >> 3;
    const int tid  = threadIdx.x;
    const int w    = tid >> 6;
    const int lane = tid & 63;
    const int bg   = lane >> 3;
    const int cg   = lane & 7;
    const int b    = (bid & 7) * 8 + bg;
    const int cbase = w * CDIM + cg * 8;
    const size_t orow = ((size_t)i * BATCH + b) * HID + cbase;
    const float* bor = bo + cbase;

    const int s0 = noff[i], s1 = noff[i + 1];
    if (s0 == s1) {
        bf16x8 ov;
        #pragma unroll
        for (int q = 0; q < 8; ++q) ov[q] = (bf16_t)gelu_f(bor[q]);
        *(bf16x8*)(Hout + orow) = ov;
        return;
    }

    float a6[8], a4[8], xi[8];
    {
        const float* ar = att + cbase;
        const bf16x8 xr = *(const bf16x8*)(XR + orow);
        #pragma unroll
        for (int q = 0; q < 8; ++q) {
            float a = ar[q];
            a6[q] = 0.6f * a; a4[q] = 0.4f * a;
            xi[q] = (float)xr[q];
        }
    }

    const bf16_t* XLb = XL + (size_t)b * HID + cbase;
    const size_t RSTR = (size_t)BATCH * HID;

    float mA = -1e30f, dA = 0.f, mB = -1e30f, dB = 0.f;
    float accA[8], accB[8];
    #pragma unroll
    for (int q = 0; q < 8; ++q) { accA[q] = 0.f; accB[q] = 0.f; }

    int jA = csrc[s0];
    int jB = csrc[(s0 + 1 < s1) ? s0 + 1 : s0];
    bf16x8 xA = *(const bf16x8*)(XLb + (size_t)jA * RSTR);
    bf16x8 xB = *(const bf16x8*)(XLb + (size_t)jB * RSTR);

    for (int e = s0; e < s1; e += 2) {
        const int nA = (e + 2 < s1) ? e + 2 : s0;
        const int nB = (e + 3 < s1) ? e + 3 : s0;
        const int jnA = csrc[nA], jnB = csrc[nB];
        const bf16x8 xnA = *(const bf16x8*)(XLb + (size_t)jnA * RSTR);
        const bf16x8 xnB = *(const bf16x8*)(XLb + (size_t)jnB * RSTR);

        float fA[8], fB[8];
        #pragma unroll
        for (int q = 0; q < 8; ++q) { fA[q] = (float)xA[q]; fB[q] = (float)xB[q]; }
        float pA = 0.f, pB = 0.f;
        #pragma unroll
        for (int q = 0; q < 8; ++q) {
            const float zA = xi[q] + fA[q];
            const float zB = xi[q] + fB[q];
            pA = fmaf(a6[q], zA, pA);
            pB = fmaf(a6[q], zB, pB);
            pA = fmaf(a4[q], __builtin_fabsf(zA), pA);
            pB = fmaf(a4[q], __builtin_fabsf(zB), pB);
        }
        pA += __shfl_xor(pA, 1, 64);  pB += __shfl_xor(pB, 1, 64);
        pA += __shfl_xor(pA, 2, 64);  pB += __shfl_xor(pB, 2, 64);
        pA += __shfl_xor(pA, 4, 64);  pB += __shfl_xor(pB, 4, 64);

        const float mnA = fmaxf(mA, pA);
        const float alA = __expf(mA - mnA);
        const float wA  = __expf(pA - mnA);
        const float vB  = (e + 1 < s1) ? 1.f : 0.f;
        const float mnB = fmaxf(mB, pB);
        const float alB = __expf(mB - mnB);
        const float wB  = __expf(pB - mnB) * vB;
        dA = dA * alA + wA;
        dB = dB * alB + wB;
        #pragma unroll
        for (int q = 0; q < 8; ++q) {
            accA[q] = fmaf(accA[q], alA, wA * fA[q]);
            accB[q] = fmaf(accB[q], alB, wB * fB[q]);
        }
        mA = mnA; mB = mnB;
        xA = xnA; xB = xnB;
    }

    const float mm = fmaxf(mA, mB);
    const float g1 = __expf(mA - mm);
    const float g2 = __expf(mB - mm);
    const float inv = 1.0f / (dA * g1 + dB * g2 + 1e-16f);
    bf16x8 ov;
    #pragma unroll
    for (int q = 0; q < 8; ++q) {
        const float o = (accA[q] * g1 + accB[q] * g2) * inv + bor[q];
        ov[q] = (bf16_t)gelu_f(o);
    }
    *(bf16x8*)(Hout + orow) = ov;
}

// ---------------------------------------------------------------------------
// Mean-pool partials: grid (64 b, 4 c); block sums nodes [c*64, c*64+64).
// ---------------------------------------------------------------------------
__global__ __launch_bounds__(256) void pool_kernel(const bf16_t* __restrict__ H1,
                                                   float* __restrict__ P) {
    const int b = blockIdx.x, c = blockIdx.y, f = threadIdx.x;
    const bf16_t* p = H1 + ((size_t)(c * 64) * BATCH + b) * HID + f;
    float s = 0.f;
    for (int n = 0; n < 64; ++n) s += (float)p[(size_t)n * BATCH * HID];
    P[((size_t)b * 4 + c) * HID + f] = s;
}

// ---------------------------------------------------------------------------
// Output proj: out = gelu(BN(pooled @ W2 + b2)), pooled from 4 partials.
// ---------------------------------------------------------------------------
__global__ __launch_bounds__(256) void final_kernel(
        const float* __restrict__ P, const float* __restrict__ W2,
        const float* __restrict__ b2, const float* __restrict__ g2,
        const float* __restrict__ be2, const float* __restrict__ m2,
        const float* __restrict__ v2, float* __restrict__ out) {
    __shared__ float pl[HID];
    const int b = blockIdx.x, f = threadIdx.x;
    float s4 = 0.f;
    #pragma unroll
    for (int c = 0; c < 4; ++c) s4 += P[((size_t)b * 4 + c) * HID + f];
    pl[f] = s4 * (1.0f / (float)NNODES);
    __syncthreads();
    float s = 0.f;
    for (int k = 0; k < HID; ++k) s += pl[k] * W2[(size_t)k * HID + f];
    s += b2[f];
    const float scale = g2[f] * rsqrtf(v2[f] + EPS_BN);
    s = (s - m2[f]) * scale + be2[f];
    out[b * HID + f] = gelu_f(s);
}

// ---------------------------------------------------------------------------
extern "C" void kernel_launch(void* const* d_in, const int* in_sizes, int n_in,
                              void* d_out, int out_size, void* d_ws, size_t ws_size,
                              hipStream_t stream) {
    const float* x    = (const float*)d_in[0];
    const int*   ei   = (const int*)d_in[1];
    const float* W1   = (const float*)d_in[2];
    const float* b1   = (const float*)d_in[3];
    const float* g1   = (const float*)d_in[4];
    const float* be1  = (const float*)d_in[5];
    const float* m1   = (const float*)d_in[6];
    const float* v1   = (const float*)d_in[7];
    const float* Wl0  = (const float*)d_in[8];
    const float* bl0  = (const float*)d_in[9];
    const float* Wr0  = (const float*)d_in[10];
    const float* br0  = (const float*)d_in[11];
    const float* att0 = (const float*)d_in[12];
    const float* bo0  = (const float*)d_in[13];
    const float* Wl1  = (const float*)d_in[14];
    const float* bl1  = (const float*)d_in[15];
    const float* Wr1  = (const float*)d_in[16];
    const float* br1  = (const float*)d_in[17];
    const float* att1 = (const float*)d_in[18];
    const float* bo1  = (const float*)d_in[19];
    const float* W2   = (const float*)d_in[20];
    const float* b2   = (const float*)d_in[21];
    const float* g2   = (const float*)d_in[22];
    const float* be2  = (const float*)d_in[23];
    const float* m2   = (const float*)d_in[24];
    const float* v2   = (const float*)d_in[25];

    char* ws = (char*)d_ws;
    const int M = BATCH * NNODES;                        // 16384
    const size_t SZ_BF = (size_t)M * HID * sizeof(bf16_t);   // 8 MB

    int*    noff = (int*)ws;                ws += 2048;
    int*    csrc = (int*)ws;                ws += 32768;
    bf16_t* W1t  = (bf16_t*)ws;             ws += 256 * 768 * 2;
    bf16_t* Wl0t = (bf16_t*)ws;             ws += 256 * 256 * 2;
    bf16_t* Wr0t = (bf16_t*)ws;             ws += 256 * 256 * 2;
    bf16_t* Wl1t = (bf16_t*)ws;             ws += 256 * 256 * 2;
    bf16_t* Wr1t = (bf16_t*)ws;             ws += 256 * 256 * 2;
    bf16_t* H    = (bf16_t*)ws;             ws += SZ_BF;   // node_proj out / edge1 out
    bf16_t* H2   = (bf16_t*)ws;             ws += SZ_BF;   // edge0 out
    bf16_t* XL   = (bf16_t*)ws;             ws += SZ_BF;   // lin_l out
    bf16_t* XR   = (bf16_t*)ws;             ws += SZ_BF;   // lin_r out
    float*  P    = (float*)ws;              ws += BATCH * 4 * HID * 4;

    prep_kernel<<<449, 256, 0, stream>>>(ei, W1, Wl0, Wr0, Wl1, Wr1,
                                         noff, csrc, W1t, Wl0t, Wr0t, Wl1t, Wr1t);

    // node_proj: H = gelu(BN(x @ W1 + b1)), batch-major A -> node-major C
    gemm_kernel<1, 0, 1, 1, 24><<<dim3(1, 512), 256, 0, stream>>>(
        x, W1t, nullptr, H, nullptr, b1, nullptr, g1, be1, m1, v1);

    // layer 0: XL = H@Wl0+bl0, XR = H@Wr0+br0 (both bf16)
    gemm_kernel<0, 1, 0, 0, 8><<<dim3(2, 512), 256, 0, stream>>>(
        H, Wl0t, Wr0t, XL, XR, bl0, br0, nullptr, nullptr, nullptr, nullptr);
    edge_kernel<<<NNODES * 8, 256, 0, stream>>>(XL, XR, att0, bo0, noff, csrc, H2);

    // layer 1
    gemm_kernel<0, 1, 0, 0, 8><<<dim3(2, 512), 256, 0, stream>>>(
        H2, Wl1t, Wr1t, XL, XR, bl1, br1, nullptr, nullptr, nullptr, nullptr);
    edge_kernel<<<NNODES * 8, 256, 0, stream>>>(XL, XR, att1, bo1, noff, csrc, H);

    pool_kernel<<<dim3(BATCH, 4), 256, 0, stream>>>(H, P);
    final_kernel<<<BATCH, 256, 0, stream>>>(P, W2, b2, g2, be2, m2, v2,
                                            (float*)d_out);
}